// Round 13
// baseline (135.768 us; speedup 1.0000x reference)
//
#include <hip/hip_runtime.h>
#include <hip/hip_bf16.h>

// ---------------- problem constants ----------------
#define BATCH   16
#define C_INF   4
#define H_IN    128
#define W_IN    128
#define HID     50
#define F_OUT   18
#define HO      120
#define WO      120
#define OH      122
#define OW      122
#define NPOS    (BATCH * HO * WO)       // 230400 = 3600 * 64
#define MBLK    64                      // positions per block (2 waves x M=32)
#define NBLKS   (NPOS / MBLK)           // 3600

// frag-packed weight blob sizes (bf16 shorts)
#define NB1     (11*4*2*64*8)           // 45056
#define NB2     (2*4*2*64*8)            // 8192
#define NB3     (2*2*2*64*8)            // 4096
#define NWF     (NB1 + NB2 + NB3)
#define WOFF    (NPOS * F_OUT)          // out3 floats

typedef float  v4f    __attribute__((ext_vector_type(4)));
typedef short  short8 __attribute__((ext_vector_type(8)));
typedef __bf16 v8bf   __attribute__((ext_vector_type(8)));
typedef int    v4i    __attribute__((ext_vector_type(4)));
typedef v4f    v4f_a4 __attribute__((aligned(4)));     // 16B load, 4B-aligned ok

__device__ inline short f2bf_hi(float x) {
    __hip_bfloat16 h = __float2bfloat16(x);      // RNE
    return __builtin_bit_cast(short, h);
}
__device__ inline float bf2f(short s) {
    __hip_bfloat16 h = __builtin_bit_cast(__hip_bfloat16, s);
    return __bfloat162float(h);
}

// slot -> k bijection for layer 1 (contiguous kj in the low 9 k-steps)
__device__ inline int slot_to_k1(int s, int qb, int e) {
    if (s < 9) {
        int pair = s*4 + qb;            // (c,ki) in [0,36)
        int c = pair/9, ki = pair - c*9;
        return c*81 + ki*9 + e;         // kj = e in [0,8)
    }
    int r = (s-9)*32 + qb*8 + e;        // remainder: kj = 8
    if (r >= 36) return -1;
    int c = r/9, ki = r - c*9;
    return c*81 + ki*9 + 8;
}

// ---------------- prep: weights ONLY ----------------
__global__ __launch_bounds__(256)
void prep_kernel(const float* __restrict__ W1, const float* __restrict__ W2,
                 const float* __restrict__ W3, short* __restrict__ wf)
{
    int i = blockIdx.x * 256 + threadIdx.x;
    if (i >= NWF) return;
    float val;
    int p;
    if (i < NB1) {
        int t = i;
        int e = t & 7, lane = (t >> 3) & 63; p = (t >> 9) & 1;
        int rest = t >> 10;                  // s*4 + u
        int u = rest & 3, s = rest >> 2;
        int k = slot_to_k1(s, lane >> 4, e);
        int n = u*16 + (lane & 15);
        val = (k >= 0 && n < HID) ? W1[k*HID + n] : 0.f;
    } else if (i < NB1 + NB2) {
        int t = i - NB1;
        int e = t & 7, lane = (t >> 3) & 63; p = (t >> 9) & 1;
        int rest = t >> 10;
        int u = rest & 3, s = rest >> 2;
        int k = s*32 + ((lane >> 4) << 3) + e;   // linear (LDS h layout)
        int n = u*16 + (lane & 15);
        val = (k < HID && n < HID) ? W2[k*HID + n] : 0.f;
    } else {
        int t = i - NB1 - NB2;
        int e = t & 7, lane = (t >> 3) & 63; p = (t >> 9) & 1;
        int rest = t >> 10;
        int u = rest & 1, s = rest >> 1;
        int k = s*32 + ((lane >> 4) << 3) + e;
        int n = u*16 + (lane & 15);
        val = (k < HID && n < F_OUT) ? W3[k*F_OUT + n] : 0.f;
    }
    short hi = f2bf_hi(val);
    wf[i] = (p == 0) ? hi : f2bf_hi(val - bf2f(hi));
}

// ---------------- fused 3-layer MLP, wave-independent, fine-grained blocks ----------------
// Block = 128 threads (2 waves), each wave M=32 (r11's proven shape), MBLK=64.
// Same total waves as r11 (7200) but half-size dispatch quanta -> smoother ramp/tail.
// h (bf16-hi) in wave-private LDS rows; zero __syncthreads.
__global__ __launch_bounds__(128, 5)
void mfma_mlp(const float* __restrict__ x,
              const float* __restrict__ b1, const float* __restrict__ b2,
              const float* __restrict__ b3,
              const short* __restrict__ wf, float* __restrict__ out3)
{
    __shared__ short h_hi[64 * 72];    // 9216 B; wave w owns rows [w*32, w*32+32)

    const int tid  = threadIdx.x;
    const int lane = tid & 63;
    const int w    = tid >> 6;         // 0..1
    const int q    = lane >> 4, col = lane & 15;
    const int mbase = blockIdx.x * MBLK;
    const int mw    = w * 32;          // this wave's row base within the block

    // hoisted bias loads (hidden behind L1 compute)
    float bias1[4], bias2[4], bias3[2];
    #pragma unroll
    for (int u = 0; u < 4; ++u) {
        int j = u*16 + col;
        bias1[u] = (j < HID) ? b1[j] : 0.f;
        bias2[u] = (j < HID) ? b2[j] : 0.f;
    }
    #pragma unroll
    for (int u = 0; u < 2; ++u) {
        int j = u*16 + col;
        bias3[u] = (j < F_OUT) ? b3[j] : 0.f;
    }

    int xbase[2];
    #pragma unroll
    for (int t = 0; t < 2; ++t) {
        int pos = mbase + mw + t*16 + col;
        int b   = pos / (HO*WO); int rem = pos - b*(HO*WO);
        int y   = rem / WO;      int xc  = rem - y*WO;
        xbase[t] = b*(C_INF*H_IN*W_IN) + y*W_IN + xc;
    }

    const v4i* B1 = (const v4i*)wf;
    const v4i* B2 = (const v4i*)(wf + NB1);
    const v4i* B3 = (const v4i*)(wf + NB1 + NB2);

    // ---------------- layer 1: K=324 (11 k-steps), N=64 ----------------
    v4f acc[2][4];
    #pragma unroll
    for (int t = 0; t < 2; ++t)
        #pragma unroll
        for (int u = 0; u < 4; ++u)
            acc[t][u] = (v4f){0.f, 0.f, 0.f, 0.f};

    // 9 octet steps: this quad's 8 k's are 8 consecutive raw-x floats (kj = 0..7)
    #pragma unroll 3
    for (int s = 0; s < 9; ++s) {
        const int pair = s*4 + q;
        const int c = pair/9, ki = pair - c*9;
        const int off = c*(H_IN*W_IN) + ki*W_IN;

        // b-frags first (long-latency hits overlap the a-frag cvt work)
        v4i bhv[4], blv[4];
        #pragma unroll
        for (int u = 0; u < 4; ++u) {
            int fb = ((s*4 + u)*2)*64 + lane;
            bhv[u] = B1[fb];
            blv[u] = B1[fb + 64];
        }

        short8 ah[2];
        #pragma unroll
        for (int t = 0; t < 2; ++t) {
            const float* p = &x[xbase[t] + off];
            v4f fa  = *(const v4f_a4*)(p);       // kj 0..3
            v4f fb2 = *(const v4f_a4*)(p + 4);   // kj 4..7
            #pragma unroll
            for (int e = 0; e < 4; ++e) {
                ah[t][e]     = f2bf_hi(fa[e]);
                ah[t][e + 4] = f2bf_hi(fb2[e]);
            }
        }
        #pragma unroll
        for (int u = 0; u < 4; ++u) {
            v8bf bh = __builtin_bit_cast(v8bf, bhv[u]);
            v8bf bl = __builtin_bit_cast(v8bf, blv[u]);
            #pragma unroll
            for (int t = 0; t < 2; ++t) {
                v8bf a_h = __builtin_bit_cast(v8bf, ah[t]);
                acc[t][u] = __builtin_amdgcn_mfma_f32_16x16x32_bf16(a_h, bh, acc[t][u], 0, 0, 0);
                acc[t][u] = __builtin_amdgcn_mfma_f32_16x16x32_bf16(a_h, bl, acc[t][u], 0, 0, 0);
            }
        }
    }
    // 2 remainder steps (kj = 8)
    #pragma unroll
    for (int sr = 0; sr < 2; ++sr) {
        const int s = 9 + sr;
        short8 ah[2];
        #pragma unroll
        for (int e = 0; e < 8; ++e) {
            int r = sr*32 + q*8 + e;
            bool valid = (r < 36);
            int c = valid ? r/9 : 0;
            int ki = r - c*9;
            int off = c*(H_IN*W_IN) + ki*W_IN + 8;
            #pragma unroll
            for (int t = 0; t < 2; ++t) {
                float v = valid ? x[xbase[t] + off] : 0.f;
                ah[t][e] = f2bf_hi(v);
            }
        }
        #pragma unroll
        for (int u = 0; u < 4; ++u) {
            int fb = ((s*4 + u)*2)*64 + lane;
            v8bf bh = __builtin_bit_cast(v8bf, B1[fb]);
            v8bf bl = __builtin_bit_cast(v8bf, B1[fb + 64]);
            #pragma unroll
            for (int t = 0; t < 2; ++t) {
                v8bf a_h = __builtin_bit_cast(v8bf, ah[t]);
                acc[t][u] = __builtin_amdgcn_mfma_f32_16x16x32_bf16(a_h, bh, acc[t][u], 0, 0, 0);
                acc[t][u] = __builtin_amdgcn_mfma_f32_16x16x32_bf16(a_h, bl, acc[t][u], 0, 0, 0);
            }
        }
    }

    // epilogue L1: + b1, relu, bf16-hi into this wave's LDS rows (no barrier needed)
    #pragma unroll
    for (int u = 0; u < 4; ++u) {
        #pragma unroll
        for (int t = 0; t < 2; ++t) {
            #pragma unroll
            for (int r = 0; r < 4; ++r) {
                float v = fmaxf(acc[t][u][r] + bias1[u], 0.f);
                int m = mw + t*16 + q*4 + r;
                h_hi[m*72 + u*16 + col] = f2bf_hi(v);
            }
        }
    }

    // ---------------- layer 2: K=50 (2 k-steps), N=64, a=hi only ----------------
    v4f acc2[2][4];
    #pragma unroll
    for (int t = 0; t < 2; ++t)
        #pragma unroll
        for (int u = 0; u < 4; ++u)
            acc2[t][u] = (v4f){0.f, 0.f, 0.f, 0.f};

    #pragma unroll
    for (int s = 0; s < 2; ++s) {
        short8 ah2[2];
        #pragma unroll
        for (int t = 0; t < 2; ++t) {
            int m = mw + t*16 + col;
            ah2[t] = *(const short8*)&h_hi[m*72 + s*32 + q*8];
        }
        #pragma unroll
        for (int u = 0; u < 4; ++u) {
            int fb = ((s*4 + u)*2)*64 + lane;
            v8bf bh = __builtin_bit_cast(v8bf, B2[fb]);
            v8bf bl = __builtin_bit_cast(v8bf, B2[fb + 64]);
            #pragma unroll
            for (int t = 0; t < 2; ++t) {
                v8bf a_h = __builtin_bit_cast(v8bf, ah2[t]);
                acc2[t][u] = __builtin_amdgcn_mfma_f32_16x16x32_bf16(a_h, bh, acc2[t][u], 0, 0, 0);
                acc2[t][u] = __builtin_amdgcn_mfma_f32_16x16x32_bf16(a_h, bl, acc2[t][u], 0, 0, 0);
            }
        }
    }

    // epilogue L2 (within-wave DS is FIFO)
    #pragma unroll
    for (int u = 0; u < 4; ++u) {
        #pragma unroll
        for (int t = 0; t < 2; ++t) {
            #pragma unroll
            for (int r = 0; r < 4; ++r) {
                float v = fmaxf(acc2[t][u][r] + bias2[u], 0.f);
                int m = mw + t*16 + q*4 + r;
                h_hi[m*72 + u*16 + col] = f2bf_hi(v);
            }
        }
    }

    // ---------------- layer 3: K=50 (2 k-steps), N=18 (pad 32), a=hi only ----------------
    v4f acc3[2][2];
    #pragma unroll
    for (int t = 0; t < 2; ++t)
        #pragma unroll
        for (int u = 0; u < 2; ++u)
            acc3[t][u] = (v4f){0.f, 0.f, 0.f, 0.f};

    #pragma unroll
    for (int s = 0; s < 2; ++s) {
        short8 ah3[2];
        #pragma unroll
        for (int t = 0; t < 2; ++t) {
            int m = mw + t*16 + col;
            ah3[t] = *(const short8*)&h_hi[m*72 + s*32 + q*8];
        }
        #pragma unroll
        for (int u = 0; u < 2; ++u) {
            int fb = ((s*2 + u)*2)*64 + lane;
            v8bf bh = __builtin_bit_cast(v8bf, B3[fb]);
            v8bf bl = __builtin_bit_cast(v8bf, B3[fb + 64]);
            #pragma unroll
            for (int t = 0; t < 2; ++t) {
                v8bf a_h = __builtin_bit_cast(v8bf, ah3[t]);
                acc3[t][u] = __builtin_amdgcn_mfma_f32_16x16x32_bf16(a_h, bh, acc3[t][u], 0, 0, 0);
                acc3[t][u] = __builtin_amdgcn_mfma_f32_16x16x32_bf16(a_h, bl, acc3[t][u], 0, 0, 0);
            }
        }
    }

    // epilogue: + b3, direct planar dwordx4 stores (rows q*4..q*4+3 contiguous)
    #pragma unroll
    for (int u = 0; u < 2; ++u) {
        int j = u*16 + col;
        if (j < F_OUT) {
            #pragma unroll
            for (int t = 0; t < 2; ++t) {
                v4f vs;
                #pragma unroll
                for (int r = 0; r < 4; ++r) vs[r] = acc3[t][u][r] + bias3[u];
                *(v4f*)&out3[j*NPOS + mbase + mw + t*16 + q*4] = vs;
            }
        }
    }
}

// ---------------- fold (overlap-add) + divide, planar coalesced reads ----------------
__global__ __launch_bounds__(256)
void fold_kernel(const float* __restrict__ out3, float* __restrict__ out)
{
    const int idx = blockIdx.x * 256 + threadIdx.x;
    const int total = BATCH * 2 * OH * OW;
    if (idx >= total) return;

    int t = idx;
    const int ox = t % OW; t /= OW;
    const int oy = t % OH; t /= OH;
    const int c  = t & 1;  t >>= 1;
    const int b  = t;

    const int ylo = max(0, oy - 2), yhi = min(HO - 1, oy);
    const int xlo = max(0, ox - 2), xhi = min(WO - 1, ox);

    float s = 0.f;
    for (int y = ylo; y <= yhi; ++y) {
        const int ki = oy - y;
        for (int xx = xlo; xx <= xhi; ++xx) {
            const int kj = ox - xx;
            const int o  = (c*3 + ki)*3 + kj;
            s += out3[o*NPOS + (b*HO + y)*WO + xx];
        }
    }
    const float div = (float)((yhi - ylo + 1) * (xhi - xlo + 1));
    out[idx] = s / div;
}

// ---------------- launch ----------------
extern "C" void kernel_launch(void* const* d_in, const int* in_sizes, int n_in,
                              void* d_out, int out_size, void* d_ws, size_t ws_size,
                              hipStream_t stream)
{
    const float* x  = (const float*)d_in[0];
    const float* W1 = (const float*)d_in[1];
    const float* b1 = (const float*)d_in[2];
    const float* W2 = (const float*)d_in[3];
    const float* b2 = (const float*)d_in[4];
    const float* W3 = (const float*)d_in[5];
    const float* b3 = (const float*)d_in[6];

    float* out3 = (float*)d_ws;                               // 16.59 MB
    short* wf   = (short*)(out3 + WOFF);                      // 112 KB

    prep_kernel<<<(NWF + 255) / 256, 256, 0, stream>>>(W1, W2, W3, wf);

    mfma_mlp<<<NBLKS, 128, 0, stream>>>(x, b1, b2, b3, wf, out3);

    const int total = BATCH * 2 * OH * OW;
    fold_kernel<<<(total + 255) / 256, 256, 0, stream>>>(out3, (float*)d_out);
}

// Round 14
// 117.094 us; speedup vs baseline: 1.1595x; 1.1595x over previous
//
#include <hip/hip_runtime.h>
#include <hip/hip_bf16.h>

// ---------------- problem constants ----------------
#define BATCH   16
#define C_INF   4
#define H_IN    128
#define W_IN    128
#define HID     50
#define F_OUT   18
#define HO      120
#define WO      120
#define OH      122
#define OW      122
#define NPOS    (BATCH * HO * WO)       // 230400 = 1800 * 128
#define MBLK    128                     // positions per block (r11 optimum)
#define NBLKS   (NPOS / MBLK)           // 1800

// frag-packed weight blob sizes (bf16 shorts)
#define NB1     (11*4*2*64*8)           // 45056
#define NB2     (2*4*2*64*8)            // 8192
#define NB3     (2*2*2*64*8)            // 4096
#define NWF     (NB1 + NB2 + NB3)
#define WOFF    (NPOS * F_OUT)          // out3 elements (bf16 shorts)

typedef float  v4f    __attribute__((ext_vector_type(4)));
typedef short  short4v __attribute__((ext_vector_type(4)));
typedef short  short8 __attribute__((ext_vector_type(8)));
typedef __bf16 v8bf   __attribute__((ext_vector_type(8)));
typedef int    v4i    __attribute__((ext_vector_type(4)));
typedef v4f    v4f_a4 __attribute__((aligned(4)));     // 16B load, 4B-aligned ok

__device__ inline short f2bf_hi(float x) {
    __hip_bfloat16 h = __float2bfloat16(x);      // RNE
    return __builtin_bit_cast(short, h);
}
__device__ inline float bf2f(short s) {
    __hip_bfloat16 h = __builtin_bit_cast(__hip_bfloat16, s);
    return __bfloat162float(h);
}

// slot -> k bijection for layer 1 (contiguous kj in the low 9 k-steps)
__device__ inline int slot_to_k1(int s, int qb, int e) {
    if (s < 9) {
        int pair = s*4 + qb;            // (c,ki) in [0,36)
        int c = pair/9, ki = pair - c*9;
        return c*81 + ki*9 + e;         // kj = e in [0,8)
    }
    int r = (s-9)*32 + qb*8 + e;        // remainder: kj = 8
    if (r >= 36) return -1;
    int c = r/9, ki = r - c*9;
    return c*81 + ki*9 + 8;
}

// ---------------- prep: weights ONLY ----------------
__global__ __launch_bounds__(256)
void prep_kernel(const float* __restrict__ W1, const float* __restrict__ W2,
                 const float* __restrict__ W3, short* __restrict__ wf)
{
    int i = blockIdx.x * 256 + threadIdx.x;
    if (i >= NWF) return;
    float val;
    int p;
    if (i < NB1) {
        int t = i;
        int e = t & 7, lane = (t >> 3) & 63; p = (t >> 9) & 1;
        int rest = t >> 10;                  // s*4 + u
        int u = rest & 3, s = rest >> 2;
        int k = slot_to_k1(s, lane >> 4, e);
        int n = u*16 + (lane & 15);
        val = (k >= 0 && n < HID) ? W1[k*HID + n] : 0.f;
    } else if (i < NB1 + NB2) {
        int t = i - NB1;
        int e = t & 7, lane = (t >> 3) & 63; p = (t >> 9) & 1;
        int rest = t >> 10;
        int u = rest & 3, s = rest >> 2;
        int k = s*32 + ((lane >> 4) << 3) + e;   // linear (LDS h layout)
        int n = u*16 + (lane & 15);
        val = (k < HID && n < HID) ? W2[k*HID + n] : 0.f;
    } else {
        int t = i - NB1 - NB2;
        int e = t & 7, lane = (t >> 3) & 63; p = (t >> 9) & 1;
        int rest = t >> 10;
        int u = rest & 1, s = rest >> 1;
        int k = s*32 + ((lane >> 4) << 3) + e;
        int n = u*16 + (lane & 15);
        val = (k < HID && n < F_OUT) ? W3[k*F_OUT + n] : 0.f;
    }
    short hi = f2bf_hi(val);
    wf[i] = (p == 0) ? hi : f2bf_hi(val - bf2f(hi));
}

// ---------------- fused 3-layer MLP, wave-independent (r11 shape) ----------------
// Block = 256 (4 waves), each wave M=32 rows x all N=64; h (bf16-hi) in wave-private
// LDS rows (FIFO, zero __syncthreads). out3 stored as bf16 (halves write traffic).
__global__ __launch_bounds__(256, 4)
void mfma_mlp(const float* __restrict__ x,
              const float* __restrict__ b1, const float* __restrict__ b2,
              const float* __restrict__ b3,
              const short* __restrict__ wf, short* __restrict__ out3)
{
    __shared__ short h_hi[128 * 72];   // 18432 B; wave w owns rows [w*32, w*32+32)

    const int tid  = threadIdx.x;
    const int lane = tid & 63;
    const int w    = tid >> 6;
    const int q    = lane >> 4, col = lane & 15;
    const int mbase = blockIdx.x * MBLK;
    const int mw    = w * 32;          // this wave's row base within the block

    // hoisted bias loads (hidden behind L1 compute)
    float bias1[4], bias2[4], bias3[2];
    #pragma unroll
    for (int u = 0; u < 4; ++u) {
        int j = u*16 + col;
        bias1[u] = (j < HID) ? b1[j] : 0.f;
        bias2[u] = (j < HID) ? b2[j] : 0.f;
    }
    #pragma unroll
    for (int u = 0; u < 2; ++u) {
        int j = u*16 + col;
        bias3[u] = (j < F_OUT) ? b3[j] : 0.f;
    }

    int xbase[2];
    #pragma unroll
    for (int t = 0; t < 2; ++t) {
        int pos = mbase + mw + t*16 + col;
        int b   = pos / (HO*WO); int rem = pos - b*(HO*WO);
        int y   = rem / WO;      int xc  = rem - y*WO;
        xbase[t] = b*(C_INF*H_IN*W_IN) + y*W_IN + xc;
    }

    const v4i* B1 = (const v4i*)wf;
    const v4i* B2 = (const v4i*)(wf + NB1);
    const v4i* B3 = (const v4i*)(wf + NB1 + NB2);

    // ---------------- layer 1: K=324 (11 k-steps), N=64 ----------------
    v4f acc[2][4];
    #pragma unroll
    for (int t = 0; t < 2; ++t)
        #pragma unroll
        for (int u = 0; u < 4; ++u)
            acc[t][u] = (v4f){0.f, 0.f, 0.f, 0.f};

    // 9 octet steps: this quad's 8 k's are 8 consecutive raw-x floats (kj = 0..7)
    #pragma unroll 3
    for (int s = 0; s < 9; ++s) {
        const int pair = s*4 + q;
        const int c = pair/9, ki = pair - c*9;
        const int off = c*(H_IN*W_IN) + ki*W_IN;

        // b-frags first (long-latency hits overlap the a-frag cvt work)
        v4i bhv[4], blv[4];
        #pragma unroll
        for (int u = 0; u < 4; ++u) {
            int fb = ((s*4 + u)*2)*64 + lane;
            bhv[u] = B1[fb];
            blv[u] = B1[fb + 64];
        }

        short8 ah[2];
        #pragma unroll
        for (int t = 0; t < 2; ++t) {
            const float* p = &x[xbase[t] + off];
            v4f fa  = *(const v4f_a4*)(p);       // kj 0..3
            v4f fb2 = *(const v4f_a4*)(p + 4);   // kj 4..7
            #pragma unroll
            for (int e = 0; e < 4; ++e) {
                ah[t][e]     = f2bf_hi(fa[e]);
                ah[t][e + 4] = f2bf_hi(fb2[e]);
            }
        }
        #pragma unroll
        for (int u = 0; u < 4; ++u) {
            v8bf bh = __builtin_bit_cast(v8bf, bhv[u]);
            v8bf bl = __builtin_bit_cast(v8bf, blv[u]);
            #pragma unroll
            for (int t = 0; t < 2; ++t) {
                v8bf a_h = __builtin_bit_cast(v8bf, ah[t]);
                acc[t][u] = __builtin_amdgcn_mfma_f32_16x16x32_bf16(a_h, bh, acc[t][u], 0, 0, 0);
                acc[t][u] = __builtin_amdgcn_mfma_f32_16x16x32_bf16(a_h, bl, acc[t][u], 0, 0, 0);
            }
        }
    }
    // 2 remainder steps (kj = 8)
    #pragma unroll
    for (int sr = 0; sr < 2; ++sr) {
        const int s = 9 + sr;
        short8 ah[2];
        #pragma unroll
        for (int e = 0; e < 8; ++e) {
            int r = sr*32 + q*8 + e;
            bool valid = (r < 36);
            int c = valid ? r/9 : 0;
            int ki = r - c*9;
            int off = c*(H_IN*W_IN) + ki*W_IN + 8;
            #pragma unroll
            for (int t = 0; t < 2; ++t) {
                float v = valid ? x[xbase[t] + off] : 0.f;
                ah[t][e] = f2bf_hi(v);
            }
        }
        #pragma unroll
        for (int u = 0; u < 4; ++u) {
            int fb = ((s*4 + u)*2)*64 + lane;
            v8bf bh = __builtin_bit_cast(v8bf, B1[fb]);
            v8bf bl = __builtin_bit_cast(v8bf, B1[fb + 64]);
            #pragma unroll
            for (int t = 0; t < 2; ++t) {
                v8bf a_h = __builtin_bit_cast(v8bf, ah[t]);
                acc[t][u] = __builtin_amdgcn_mfma_f32_16x16x32_bf16(a_h, bh, acc[t][u], 0, 0, 0);
                acc[t][u] = __builtin_amdgcn_mfma_f32_16x16x32_bf16(a_h, bl, acc[t][u], 0, 0, 0);
            }
        }
    }

    // epilogue L1: + b1, relu, bf16-hi into this wave's LDS rows (no barrier needed)
    #pragma unroll
    for (int u = 0; u < 4; ++u) {
        #pragma unroll
        for (int t = 0; t < 2; ++t) {
            #pragma unroll
            for (int r = 0; r < 4; ++r) {
                float v = fmaxf(acc[t][u][r] + bias1[u], 0.f);
                int m = mw + t*16 + q*4 + r;
                h_hi[m*72 + u*16 + col] = f2bf_hi(v);
            }
        }
    }

    // ---------------- layer 2: K=50 (2 k-steps), N=64, a=hi only ----------------
    v4f acc2[2][4];
    #pragma unroll
    for (int t = 0; t < 2; ++t)
        #pragma unroll
        for (int u = 0; u < 4; ++u)
            acc2[t][u] = (v4f){0.f, 0.f, 0.f, 0.f};

    #pragma unroll
    for (int s = 0; s < 2; ++s) {
        short8 ah2[2];
        #pragma unroll
        for (int t = 0; t < 2; ++t) {
            int m = mw + t*16 + col;
            ah2[t] = *(const short8*)&h_hi[m*72 + s*32 + q*8];
        }
        #pragma unroll
        for (int u = 0; u < 4; ++u) {
            int fb = ((s*4 + u)*2)*64 + lane;
            v8bf bh = __builtin_bit_cast(v8bf, B2[fb]);
            v8bf bl = __builtin_bit_cast(v8bf, B2[fb + 64]);
            #pragma unroll
            for (int t = 0; t < 2; ++t) {
                v8bf a_h = __builtin_bit_cast(v8bf, ah2[t]);
                acc2[t][u] = __builtin_amdgcn_mfma_f32_16x16x32_bf16(a_h, bh, acc2[t][u], 0, 0, 0);
                acc2[t][u] = __builtin_amdgcn_mfma_f32_16x16x32_bf16(a_h, bl, acc2[t][u], 0, 0, 0);
            }
        }
    }

    // epilogue L2 (within-wave DS is FIFO)
    #pragma unroll
    for (int u = 0; u < 4; ++u) {
        #pragma unroll
        for (int t = 0; t < 2; ++t) {
            #pragma unroll
            for (int r = 0; r < 4; ++r) {
                float v = fmaxf(acc2[t][u][r] + bias2[u], 0.f);
                int m = mw + t*16 + q*4 + r;
                h_hi[m*72 + u*16 + col] = f2bf_hi(v);
            }
        }
    }

    // ---------------- layer 3: K=50 (2 k-steps), N=18 (pad 32), a=hi only ----------------
    v4f acc3[2][2];
    #pragma unroll
    for (int t = 0; t < 2; ++t)
        #pragma unroll
        for (int u = 0; u < 2; ++u)
            acc3[t][u] = (v4f){0.f, 0.f, 0.f, 0.f};

    #pragma unroll
    for (int s = 0; s < 2; ++s) {
        short8 ah3[2];
        #pragma unroll
        for (int t = 0; t < 2; ++t) {
            int m = mw + t*16 + col;
            ah3[t] = *(const short8*)&h_hi[m*72 + s*32 + q*8];
        }
        #pragma unroll
        for (int u = 0; u < 2; ++u) {
            int fb = ((s*2 + u)*2)*64 + lane;
            v8bf bh = __builtin_bit_cast(v8bf, B3[fb]);
            v8bf bl = __builtin_bit_cast(v8bf, B3[fb + 64]);
            #pragma unroll
            for (int t = 0; t < 2; ++t) {
                v8bf a_h = __builtin_bit_cast(v8bf, ah3[t]);
                acc3[t][u] = __builtin_amdgcn_mfma_f32_16x16x32_bf16(a_h, bh, acc3[t][u], 0, 0, 0);
                acc3[t][u] = __builtin_amdgcn_mfma_f32_16x16x32_bf16(a_h, bl, acc3[t][u], 0, 0, 0);
            }
        }
    }

    // epilogue: + b3, bf16-pack, planar 8-B stores (rows q*4..q*4+3 contiguous)
    #pragma unroll
    for (int u = 0; u < 2; ++u) {
        int j = u*16 + col;
        if (j < F_OUT) {
            #pragma unroll
            for (int t = 0; t < 2; ++t) {
                short4v vs;
                #pragma unroll
                for (int r = 0; r < 4; ++r) vs[r] = f2bf_hi(acc3[t][u][r] + bias3[u]);
                *(short4v*)&out3[j*NPOS + mbase + mw + t*16 + q*4] = vs;
            }
        }
    }
}

// ---------------- fold (overlap-add) + divide, planar bf16 reads ----------------
__global__ __launch_bounds__(256)
void fold_kernel(const short* __restrict__ out3, float* __restrict__ out)
{
    const int idx = blockIdx.x * 256 + threadIdx.x;
    const int total = BATCH * 2 * OH * OW;
    if (idx >= total) return;

    int t = idx;
    const int ox = t % OW; t /= OW;
    const int oy = t % OH; t /= OH;
    const int c  = t & 1;  t >>= 1;
    const int b  = t;

    const int ylo = max(0, oy - 2), yhi = min(HO - 1, oy);
    const int xlo = max(0, ox - 2), xhi = min(WO - 1, ox);

    float s = 0.f;
    for (int y = ylo; y <= yhi; ++y) {
        const int ki = oy - y;
        for (int xx = xlo; xx <= xhi; ++xx) {
            const int kj = ox - xx;
            const int o  = (c*3 + ki)*3 + kj;
            s += bf2f(out3[o*NPOS + (b*HO + y)*WO + xx]);
        }
    }
    const float div = (float)((yhi - ylo + 1) * (xhi - xlo + 1));
    out[idx] = s / div;
}

// ---------------- launch ----------------
extern "C" void kernel_launch(void* const* d_in, const int* in_sizes, int n_in,
                              void* d_out, int out_size, void* d_ws, size_t ws_size,
                              hipStream_t stream)
{
    const float* x  = (const float*)d_in[0];
    const float* W1 = (const float*)d_in[1];
    const float* b1 = (const float*)d_in[2];
    const float* W2 = (const float*)d_in[3];
    const float* b2 = (const float*)d_in[4];
    const float* W3 = (const float*)d_in[5];
    const float* b3 = (const float*)d_in[6];

    short* out3 = (short*)d_ws;                               // 8.29 MB (bf16)
    short* wf   = out3 + WOFF;                                // 112 KB (16B-aligned)

    prep_kernel<<<(NWF + 255) / 256, 256, 0, stream>>>(W1, W2, W3, wf);

    mfma_mlp<<<NBLKS, 256, 0, stream>>>(x, b1, b2, b3, wf, out3);

    const int total = BATCH * 2 * OH * OW;
    fold_kernel<<<(total + 255) / 256, 256, 0, stream>>>(out3, (float*)d_out);
}